// Round 1
// baseline (464.196 us; speedup 1.0000x reference)
//
#include <hip/hip_runtime.h>
#include <hip/hip_bf16.h>
#include <math.h>

#define NUM_ENT 100000
#define DIM 768
#define BATCH 4096
#define INV_TAU 20.0f
#define QSCALE 16.0f                                   // pre-scale before fp8 quant
#define LOGIT_SCALE (INV_TAU / (QSCALE * QSCALE))      // undo QSCALE^2 after MFMA

typedef __attribute__((ext_vector_type(4))) float f32x4;    // MFMA accum
typedef __attribute__((ext_vector_type(8))) int   i32x8;    // 32B fp8 MFMA operand
#define UNIT_SCALE 0x7f7f7f7f                               // E8M0 127 = 2^0 in every byte

// ------- Kernel 1: gather + L2-normalize -> fp8 e4m3 (scaled by 16) ---------
__global__ __launch_bounds__(256) void gather_norm(
    const float* __restrict__ emb, const int* __restrict__ links,
    unsigned char* __restrict__ hn1, unsigned char* __restrict__ hn2)
{
    int rowId = blockIdx.x;          // 0 .. 2*BATCH-1
    int b     = rowId >> 1;
    int which = rowId & 1;
    int src   = links[2 * b + which];
    const float* srcRow = emb + (size_t)src * DIM;

    int t = threadIdx.x;
    float4 v = make_float4(0.f, 0.f, 0.f, 0.f);
    float ss = 0.f;
    if (t < DIM / 4) {               // 192 threads load float4 each
        v = ((const float4*)srcRow)[t];
        ss = v.x * v.x + v.y * v.y + v.z * v.z + v.w * v.w;
    }
    #pragma unroll
    for (int off = 32; off >= 1; off >>= 1) ss += __shfl_xor(ss, off);
    __shared__ float wsum[4];
    if ((t & 63) == 0) wsum[t >> 6] = ss;
    __syncthreads();
    float tot = wsum[0] + wsum[1] + wsum[2] + wsum[3];
    float scale = rsqrtf(tot) * QSCALE;

    if (t < DIM / 4) {
        unsigned char* dst = (which ? hn2 : hn1) + (size_t)b * DIM;
        int p = __builtin_amdgcn_cvt_pk_fp8_f32(v.x * scale, v.y * scale, 0, false);
        p     = __builtin_amdgcn_cvt_pk_fp8_f32(v.z * scale, v.w * scale, p, true);
        ((unsigned int*)dst)[t] = (unsigned int)p;
    }
}

// ------- Kernel 2: symmetric gram (MX-fp8 MFMA, K=128) + exp row/col-sum ----
// grid: (32 colTile, 32 rowTile, 3 matrices). block: 256 (4 waves).
// matId 0: ab = h1 x h2^T  full     : rowsum->S_a, colsum->S_b, diag capture
// matId 1: aa = h1 x h1^T  upper-tri: rowsum->S_a[gi]; off-diag also colsum->S_a[gj]
// matId 2: bb = h2 x h2^T  upper-tri: rowsum->S_b[gi]; off-diag also colsum->S_b[gj]
//
// v2 vs v1: BK 32->128 with mfma_scale_f32_16x16x128_f8f6f4 (unit E8M0 scales):
//   - 2.27x MFMA rate (4661 vs 2047 TF ubench), 6 K-iters / 12 barriers (was 24/48).
//   - LDS rows are 128B (full 32-bank period): 16B chunk c of row r is stored at
//     position (c+r)&7. global_load_lds writes LDS linearly, so the permutation is
//     applied on the per-lane GLOBAL source address (G21); ds_read_b128 applies the
//     same XOR -> 2-way bank conflict (free, m136).
//   - C/D layout of the 16x16 shape is unchanged (shape-determined), epilogue reused.
__global__ __launch_bounds__(256) void gram_sym(
    const unsigned char* __restrict__ hn1, const unsigned char* __restrict__ hn2,
    float* __restrict__ S, float* __restrict__ diag)
{
    const int ct = blockIdx.x;
    const int rt = blockIdx.y;
    const int matId = blockIdx.z;
    if (matId > 0 && ct < rt) return;   // symmetric matrices: upper triangle only

    const unsigned char* A  = (matId == 2) ? hn2 : hn1;
    const unsigned char* Bm = (matId == 1) ? hn1 : hn2;
    const int  rowTarget = (matId == 2) ? 1 : 0;
    const int  colTarget = (matId == 1) ? 0 : 1;
    const bool maskDiag  = (matId > 0) && (rt == ct);
    const bool doColsum  = (matId == 0) || (rt != ct);
    const bool captureDiag = (matId == 0);

    __shared__ unsigned char sA[128 * 128];   // 16 KB (fp8: 128 rows x 128 K-bytes)
    __shared__ unsigned char sB[128 * 128];   // 16 KB

    const int t    = threadIdx.x;
    const int lane = t & 63;
    const int wave = t >> 6;
    const int wm   = wave >> 1, wn = wave & 1;
    const int quad = lane >> 4, l16 = lane & 15;
    const int row0 = rt * 128;
    const int col0 = ct * 128;

    f32x4 acc[4][4];
    #pragma unroll
    for (int im = 0; im < 4; ++im)
        #pragma unroll
        for (int jn = 0; jn < 4; ++jn)
            acc[im][jn] = (f32x4){0.f, 0.f, 0.f, 0.f};

    for (int kk = 0; kk < DIM; kk += 128) {
        // stage 128x128B fp8 tiles: 4 rounds x 256 threads x 16B per matrix.
        // chunk id idx = rd*256+t -> row r=idx>>3, LDS position p=idx&7;
        // content there is logical chunk c=(p-r)&7 (inverse of read-side XOR).
        #pragma unroll
        for (int rd = 0; rd < 4; ++rd) {
            int idx = rd * 256 + t;
            int r   = idx >> 3;
            int p   = idx & 7;
            int c   = (p - r) & 7;
            const unsigned char* ga = A  + (size_t)(row0 + r) * DIM + kk + c * 16;
            const unsigned char* gb = Bm + (size_t)(col0 + r) * DIM + kk + c * 16;
            __builtin_amdgcn_global_load_lds(
                (const __attribute__((address_space(1))) void*)ga,
                (__attribute__((address_space(3))) void*)(sA + idx * 16), 16, 0, 0);
            __builtin_amdgcn_global_load_lds(
                (const __attribute__((address_space(1))) void*)gb,
                (__attribute__((address_space(3))) void*)(sB + idx * 16), 16, 0, 0);
        }
        __syncthreads();

        // fragment reads: lane holds 32 contiguous K-bytes (k = quad*32 + j) of its
        // row; two ds_read_b128 at swizzled positions (cb+rr)&7, (cb+1+rr)&7.
        const int cb = quad * 2;
        i32x8 bf[4];
        #pragma unroll
        for (int jn = 0; jn < 4; ++jn) {
            int rr = wn * 64 + jn * 16 + l16;
            const int4 x0 = *(const int4*)&sB[rr * 128 + ((cb + rr) & 7) * 16];
            const int4 x1 = *(const int4*)&sB[rr * 128 + ((cb + 1 + rr) & 7) * 16];
            bf[jn] = (i32x8){x0.x, x0.y, x0.z, x0.w, x1.x, x1.y, x1.z, x1.w};
        }
        #pragma unroll
        for (int im = 0; im < 4; ++im) {
            int rr = wm * 64 + im * 16 + l16;
            const int4 x0 = *(const int4*)&sA[rr * 128 + ((cb + rr) & 7) * 16];
            const int4 x1 = *(const int4*)&sA[rr * 128 + ((cb + 1 + rr) & 7) * 16];
            i32x8 af = (i32x8){x0.x, x0.y, x0.z, x0.w, x1.x, x1.y, x1.z, x1.w};
            #pragma unroll
            for (int jn = 0; jn < 4; ++jn)
                acc[im][jn] = __builtin_amdgcn_mfma_scale_f32_16x16x128_f8f6f4(
                    af, bf[jn], acc[im][jn],
                    0, 0,                    // cbsz=fp8(e4m3), blgp=fp8(e4m3)
                    0, UNIT_SCALE,           // opsel_a, scale_a = 1.0
                    0, UNIT_SCALE);          // opsel_b, scale_b = 1.0
        }
        __syncthreads();
    }

    // epilogue: logits, exp, row sums (+ col sums), diag capture/mask
    float csum[4] = {0.f, 0.f, 0.f, 0.f};
    #pragma unroll
    for (int im = 0; im < 4; ++im) {
        #pragma unroll
        for (int r = 0; r < 4; ++r) {
            const int gi = row0 + wm * 64 + im * 16 + quad * 4 + r;
            float rsum = 0.f;
            #pragma unroll
            for (int jn = 0; jn < 4; ++jn) {
                const int gj = col0 + wn * 64 + jn * 16 + l16;
                float logit = acc[im][jn][r] * LOGIT_SCALE;
                bool isDiag = (gi == gj);
                if (captureDiag && isDiag) diag[gi] = logit;
                float e = __expf(logit);
                if (maskDiag && isDiag) e = 0.f;
                rsum += e;
                csum[jn] += e;
            }
            rsum += __shfl_xor(rsum, 1);
            rsum += __shfl_xor(rsum, 2);
            rsum += __shfl_xor(rsum, 4);
            rsum += __shfl_xor(rsum, 8);
            if (l16 == 0) atomicAdd(&S[rowTarget * BATCH + gi], rsum);
        }
    }
    if (doColsum) {
        #pragma unroll
        for (int jn = 0; jn < 4; ++jn) {
            float c = csum[jn];
            c += __shfl_xor(c, 16);
            c += __shfl_xor(c, 32);
            if (quad == 0) {
                const int gj = col0 + wn * 64 + jn * 16 + l16;
                atomicAdd(&S[colTarget * BATCH + gj], c);
            }
        }
    }
}

// ---------------- Kernel 3: finalize loss (single block) --------------------
__global__ __launch_bounds__(256) void finalize(
    const float* __restrict__ S, const float* __restrict__ diag,
    float* __restrict__ out)
{
    int t = threadIdx.x;
    float local = 0.f;
    for (int i = t; i < BATCH; i += 256) {
        float lse_a = logf(S[i]);
        float lse_b = logf(S[BATCH + i]);
        local += 0.5f * (lse_a + lse_b) - diag[i];
    }
    #pragma unroll
    for (int off = 32; off >= 1; off >>= 1) local += __shfl_xor(local, off);
    __shared__ float wsum[4];
    if ((t & 63) == 0) wsum[t >> 6] = local;
    __syncthreads();
    if (t == 0) out[0] = (wsum[0] + wsum[1] + wsum[2] + wsum[3]) / (float)BATCH;
}

extern "C" void kernel_launch(void* const* d_in, const int* in_sizes, int n_in,
                              void* d_out, int out_size, void* d_ws, size_t ws_size,
                              hipStream_t stream)
{
    const float* emb  = (const float*)d_in[0];
    const int* links  = (const int*)d_in[1];

    char* ws = (char*)d_ws;
    unsigned char* hn1 = (unsigned char*)ws;                         // 3.1 MB fp8
    unsigned char* hn2 = (unsigned char*)(ws + (size_t)BATCH * DIM); // 3.1 MB fp8
    float* S    = (float*)(ws + (size_t)BATCH * DIM * 2);            // 2*4096 f32
    float* diag = (float*)(ws + (size_t)BATCH * DIM * 2 + 2 * BATCH * 4); // 4096 f32

    hipMemsetAsync(S, 0, 2 * BATCH * sizeof(float), stream);

    gather_norm<<<dim3(2 * BATCH), 256, 0, stream>>>(emb, links, hn1, hn2);
    gram_sym<<<dim3(32, 32, 3), 256, 0, stream>>>(hn1, hn2, S, diag);
    finalize<<<1, 256, 0, stream>>>(S, diag, (float*)d_out);
}

// Round 2
// 435.212 us; speedup vs baseline: 1.0666x; 1.0666x over previous
//
#include <hip/hip_runtime.h>
#include <hip/hip_bf16.h>
#include <math.h>

#define NUM_ENT 100000
#define DIM 768
#define BATCH 4096
#define INV_TAU 20.0f
#define QSCALE 16.0f                                   // pre-scale before fp8 quant
#define LOGIT_SCALE (INV_TAU / (QSCALE * QSCALE))      // undo QSCALE^2 after MFMA

typedef __attribute__((ext_vector_type(4))) float f32x4;    // MFMA accum

// ------- Kernel 1: gather + L2-normalize -> fp8 e4m3 (scaled by 16) ---------
__global__ __launch_bounds__(256) void gather_norm(
    const float* __restrict__ emb, const int* __restrict__ links,
    unsigned char* __restrict__ hn1, unsigned char* __restrict__ hn2)
{
    int rowId = blockIdx.x;          // 0 .. 2*BATCH-1
    int b     = rowId >> 1;
    int which = rowId & 1;
    int src   = links[2 * b + which];
    const float* srcRow = emb + (size_t)src * DIM;

    int t = threadIdx.x;
    float4 v = make_float4(0.f, 0.f, 0.f, 0.f);
    float ss = 0.f;
    if (t < DIM / 4) {               // 192 threads load float4 each
        v = ((const float4*)srcRow)[t];
        ss = v.x * v.x + v.y * v.y + v.z * v.z + v.w * v.w;
    }
    #pragma unroll
    for (int off = 32; off >= 1; off >>= 1) ss += __shfl_xor(ss, off);
    __shared__ float wsum[4];
    if ((t & 63) == 0) wsum[t >> 6] = ss;
    __syncthreads();
    float tot = wsum[0] + wsum[1] + wsum[2] + wsum[3];
    float scale = rsqrtf(tot) * QSCALE;

    if (t < DIM / 4) {
        unsigned char* dst = (which ? hn2 : hn1) + (size_t)b * DIM;
        int p = __builtin_amdgcn_cvt_pk_fp8_f32(v.x * scale, v.y * scale, 0, false);
        p     = __builtin_amdgcn_cvt_pk_fp8_f32(v.z * scale, v.w * scale, p, true);
        ((unsigned int*)dst)[t] = (unsigned int)p;
    }
}

// ------- Kernel 2: symmetric gram (fp8 MFMA) + exp row/col-sum --------------
// grid: (32 colTile, 32 rowTile, 3 matrices). block: 256 (4 waves).
// matId 0: ab = h1 x h2^T  full     : rowsum->S_a, colsum->S_b, diag capture
// matId 1: aa = h1 x h1^T  upper-tri: rowsum->S_a[gi]; off-diag also colsum->S_a[gj]
// matId 2: bb = h2 x h2^T  upper-tri: rowsum->S_b[gi]; off-diag also colsum->S_b[gj]
//
// v3 vs v0 (the 430us kernel): T3-minimal double-buffer. BK 32->64, LDS
// [2 buf][2 kb][128 r][32 B] per matrix (32 KB total). Next-tile global_load_lds
// issued BEFORE this tile's ds_read+MFMA, so the vmcnt(0) drain that
// __syncthreads emits lands after ~400 cycles of compute cover. Barriers
// 48 -> 13. MFMA path / fragment swizzle / epilogue byte-identical to v0
// (MX mfma_scale experiment of v2 regressed +34us: 8-VGPR operand pressure).
__global__ __launch_bounds__(256) void gram_sym(
    const unsigned char* __restrict__ hn1, const unsigned char* __restrict__ hn2,
    float* __restrict__ S, float* __restrict__ diag)
{
    const int ct = blockIdx.x;
    const int rt = blockIdx.y;
    const int matId = blockIdx.z;
    if (matId > 0 && ct < rt) return;   // symmetric matrices: upper triangle only

    const unsigned char* A  = (matId == 2) ? hn2 : hn1;
    const unsigned char* Bm = (matId == 1) ? hn1 : hn2;
    const int  rowTarget = (matId == 2) ? 1 : 0;
    const int  colTarget = (matId == 1) ? 0 : 1;
    const bool maskDiag  = (matId > 0) && (rt == ct);
    const bool doColsum  = (matId == 0) || (rt != ct);
    const bool captureDiag = (matId == 0);

    // [buf][kblock][row][32B]; same 16B-half rotation as v0 within each 32B block
    __shared__ unsigned char sA[2][2][128][32];   // 16 KB
    __shared__ unsigned char sB[2][2][128][32];   // 16 KB

    const int t    = threadIdx.x;
    const int lane = t & 63;
    const int wave = t >> 6;
    const int wm   = wave >> 1, wn = wave & 1;
    const int quad = lane >> 4, l16 = lane & 15;
    const int row0 = rt * 128;
    const int col0 = ct * 128;

    f32x4 acc[4][4];
    #pragma unroll
    for (int im = 0; im < 4; ++im)
        #pragma unroll
        for (int jn = 0; jn < 4; ++jn)
            acc[im][jn] = (f32x4){0.f, 0.f, 0.f, 0.f};

    // staging geometry: thread t owns row r = t>>1, 16B half h = t&1 of each
    // 32B k-block; half position rotated by (r>>2)&1 (v0's verified scheme).
    const int r    = t >> 1;
    const int h    = t & 1;
    const int koff = ((h + ((r >> 2) & 1)) & 1) * 16;
    const unsigned char* gA = A  + (size_t)(row0 + r) * DIM + koff;
    const unsigned char* gB = Bm + (size_t)(col0 + r) * DIM + koff;

    auto stage = [&](int buf, int kk) {
        #pragma unroll
        for (int kb = 0; kb < 2; ++kb) {
            __builtin_amdgcn_global_load_lds(
                (const __attribute__((address_space(1))) void*)(gA + kk + kb * 32),
                (__attribute__((address_space(3))) void*)&sA[buf][kb][r][h * 16], 16, 0, 0);
            __builtin_amdgcn_global_load_lds(
                (const __attribute__((address_space(1))) void*)(gB + kk + kb * 32),
                (__attribute__((address_space(3))) void*)&sB[buf][kb][r][h * 16], 16, 0, 0);
        }
    };

    const int NT = DIM / 64;            // 12 K-iterations
    stage(0, 0);
    __syncthreads();

    const int hk = quad >> 1, q8 = (quad & 1) * 8;
    for (int it = 0; it < NT; ++it) {
        const int buf = it & 1;
        if (it + 1 < NT) stage(buf ^ 1, (it + 1) * 64);   // prefetch next tile

        #pragma unroll
        for (int kb = 0; kb < 2; ++kb) {
            long long bfr[4];
            #pragma unroll
            for (int jn = 0; jn < 4; ++jn) {
                int row = wn * 64 + jn * 16 + l16;
                int hl  = (hk + ((row >> 2) & 1)) & 1;
                bfr[jn] = *(const long long*)&sB[buf][kb][row][hl * 16 + q8];
            }
            #pragma unroll
            for (int im = 0; im < 4; ++im) {
                int row = wm * 64 + im * 16 + l16;
                int hl  = (hk + ((row >> 2) & 1)) & 1;
                long long af = *(const long long*)&sA[buf][kb][row][hl * 16 + q8];
                #pragma unroll
                for (int jn = 0; jn < 4; ++jn)
                    acc[im][jn] = __builtin_amdgcn_mfma_f32_16x16x32_fp8_fp8(
                        af, bfr[jn], acc[im][jn], 0, 0, 0);
            }
        }
        __syncthreads();   // vmcnt(0) drain here covers the prefetch, after compute
    }

    // epilogue: logits, exp, row sums (+ col sums), diag capture/mask
    float csum[4] = {0.f, 0.f, 0.f, 0.f};
    #pragma unroll
    for (int im = 0; im < 4; ++im) {
        #pragma unroll
        for (int rr = 0; rr < 4; ++rr) {
            const int gi = row0 + wm * 64 + im * 16 + quad * 4 + rr;
            float rsum = 0.f;
            #pragma unroll
            for (int jn = 0; jn < 4; ++jn) {
                const int gj = col0 + wn * 64 + jn * 16 + l16;
                float logit = acc[im][jn][rr] * LOGIT_SCALE;
                bool isDiag = (gi == gj);
                if (captureDiag && isDiag) diag[gi] = logit;
                float e = __expf(logit);
                if (maskDiag && isDiag) e = 0.f;
                rsum += e;
                csum[jn] += e;
            }
            rsum += __shfl_xor(rsum, 1);
            rsum += __shfl_xor(rsum, 2);
            rsum += __shfl_xor(rsum, 4);
            rsum += __shfl_xor(rsum, 8);
            if (l16 == 0) atomicAdd(&S[rowTarget * BATCH + gi], rsum);
        }
    }
    if (doColsum) {
        #pragma unroll
        for (int jn = 0; jn < 4; ++jn) {
            float c = csum[jn];
            c += __shfl_xor(c, 16);
            c += __shfl_xor(c, 32);
            if (quad == 0) {
                const int gj = col0 + wn * 64 + jn * 16 + l16;
                atomicAdd(&S[colTarget * BATCH + gj], c);
            }
        }
    }
}

// ---------------- Kernel 3: finalize loss (single block) --------------------
__global__ __launch_bounds__(256) void finalize(
    const float* __restrict__ S, const float* __restrict__ diag,
    float* __restrict__ out)
{
    int t = threadIdx.x;
    float local = 0.f;
    for (int i = t; i < BATCH; i += 256) {
        float lse_a = logf(S[i]);
        float lse_b = logf(S[BATCH + i]);
        local += 0.5f * (lse_a + lse_b) - diag[i];
    }
    #pragma unroll
    for (int off = 32; off >= 1; off >>= 1) local += __shfl_xor(local, off);
    __shared__ float wsum[4];
    if ((t & 63) == 0) wsum[t >> 6] = local;
    __syncthreads();
    if (t == 0) out[0] = (wsum[0] + wsum[1] + wsum[2] + wsum[3]) / (float)BATCH;
}

extern "C" void kernel_launch(void* const* d_in, const int* in_sizes, int n_in,
                              void* d_out, int out_size, void* d_ws, size_t ws_size,
                              hipStream_t stream)
{
    const float* emb  = (const float*)d_in[0];
    const int* links  = (const int*)d_in[1];

    char* ws = (char*)d_ws;
    unsigned char* hn1 = (unsigned char*)ws;                         // 3.1 MB fp8
    unsigned char* hn2 = (unsigned char*)(ws + (size_t)BATCH * DIM); // 3.1 MB fp8
    float* S    = (float*)(ws + (size_t)BATCH * DIM * 2);            // 2*4096 f32
    float* diag = (float*)(ws + (size_t)BATCH * DIM * 2 + 2 * BATCH * 4); // 4096 f32

    hipMemsetAsync(S, 0, 2 * BATCH * sizeof(float), stream);

    gather_norm<<<dim3(2 * BATCH), 256, 0, stream>>>(emb, links, hn1, hn2);
    gram_sym<<<dim3(32, 32, 3), 256, 0, stream>>>(hn1, hn2, S, diag);
    finalize<<<1, 256, 0, stream>>>(S, diag, (float*)d_out);
}

// Round 3
// 426.091 us; speedup vs baseline: 1.0894x; 1.0214x over previous
//
#include <hip/hip_runtime.h>
#include <hip/hip_bf16.h>
#include <math.h>

#define NUM_ENT 100000
#define DIM 768
#define BATCH 4096
#define INV_TAU 20.0f
#define QSCALE 16.0f                                   // pre-scale before fp8 quant
#define LOGIT_SCALE (INV_TAU / (QSCALE * QSCALE))      // undo QSCALE^2 after MFMA

typedef __attribute__((ext_vector_type(4))) float f32x4;    // MFMA accum

// ------- Kernel 1: gather + L2-normalize -> fp8 e4m3 (scaled by 16) ---------
// v4: one WAVE per row (was one 256-thread block per row with 64 idle lanes +
// LDS reduce). 4 rows/block, lane loads 3x float4, pure shfl_xor reduce.
__global__ __launch_bounds__(256) void gather_norm(
    const float* __restrict__ emb, const int* __restrict__ links,
    unsigned char* __restrict__ hn1, unsigned char* __restrict__ hn2)
{
    const int t    = threadIdx.x;
    const int wave = t >> 6;
    const int lane = t & 63;
    const int rowId = blockIdx.x * 4 + wave;   // 0 .. 2*BATCH-1
    const int b     = rowId >> 1;
    const int which = rowId & 1;
    const int src   = links[2 * b + which];
    const float* srcRow = emb + (size_t)src * DIM;

    float4 v0 = ((const float4*)srcRow)[lane];
    float4 v1 = ((const float4*)srcRow)[lane + 64];
    float4 v2 = ((const float4*)srcRow)[lane + 128];

    float ss = v0.x * v0.x + v0.y * v0.y + v0.z * v0.z + v0.w * v0.w
             + v1.x * v1.x + v1.y * v1.y + v1.z * v1.z + v1.w * v1.w
             + v2.x * v2.x + v2.y * v2.y + v2.z * v2.z + v2.w * v2.w;
    #pragma unroll
    for (int off = 32; off >= 1; off >>= 1) ss += __shfl_xor(ss, off);
    const float scale = rsqrtf(ss) * QSCALE;

    unsigned char* dst = (which ? hn2 : hn1) + (size_t)b * DIM;
    int p0 = __builtin_amdgcn_cvt_pk_fp8_f32(v0.x * scale, v0.y * scale, 0, false);
    p0     = __builtin_amdgcn_cvt_pk_fp8_f32(v0.z * scale, v0.w * scale, p0, true);
    int p1 = __builtin_amdgcn_cvt_pk_fp8_f32(v1.x * scale, v1.y * scale, 0, false);
    p1     = __builtin_amdgcn_cvt_pk_fp8_f32(v1.z * scale, v1.w * scale, p1, true);
    int p2 = __builtin_amdgcn_cvt_pk_fp8_f32(v2.x * scale, v2.y * scale, 0, false);
    p2     = __builtin_amdgcn_cvt_pk_fp8_f32(v2.z * scale, v2.w * scale, p2, true);
    ((unsigned int*)dst)[lane]       = (unsigned int)p0;
    ((unsigned int*)dst)[lane + 64]  = (unsigned int)p1;
    ((unsigned int*)dst)[lane + 128] = (unsigned int)p2;
}

// ------- Kernel 2: symmetric gram (fp8 MFMA) + exp row/col-sum --------------
// grid: (32 colTile, 32 rowTile, 3 matrices). block: 256 (4 waves).
// matId 0: ab = h1 x h2^T  full     : rowsum->S_a, colsum->S_b, diag capture
// matId 1: aa = h1 x h1^T  upper-tri: rowsum->S_a[gi]; off-diag also colsum->S_a[gj]
// matId 2: bb = h2 x h2^T  upper-tri: rowsum->S_b[gi]; off-diag also colsum->S_b[gj]
// v4: byte-identical revert to the 430.1us-verified v0 structure. Both the
// MX-K128 rewrite (+34us: 8-VGPR operand pressure) and the BK=64 double-buffer
// (+5us: 4x LDS, prefetch VALU) regressed -- this 2-barrier BK=32 loop is the
// measured local optimum for this 24-iter K-depth.
__global__ __launch_bounds__(256) void gram_sym(
    const unsigned char* __restrict__ hn1, const unsigned char* __restrict__ hn2,
    float* __restrict__ S, float* __restrict__ diag)
{
    const int ct = blockIdx.x;
    const int rt = blockIdx.y;
    const int matId = blockIdx.z;
    if (matId > 0 && ct < rt) return;   // symmetric matrices: upper triangle only

    const unsigned char* A  = (matId == 2) ? hn2 : hn1;
    const unsigned char* Bm = (matId == 1) ? hn1 : hn2;
    const int  rowTarget = (matId == 2) ? 1 : 0;
    const int  colTarget = (matId == 1) ? 0 : 1;
    const bool maskDiag  = (matId > 0) && (rt == ct);
    const bool doColsum  = (matId == 0) || (rt != ct);
    const bool captureDiag = (matId == 0);

    __shared__ unsigned char sA[128 * 32];   // 4 KB (fp8: 128 rows x 32 K-bytes)
    __shared__ unsigned char sB[128 * 32];   // 4 KB

    const int t    = threadIdx.x;
    const int lane = t & 63;
    const int wave = t >> 6;
    const int wm   = wave >> 1, wn = wave & 1;
    const int quad = lane >> 4, l16 = lane & 15;
    const int row0 = rt * 128;
    const int col0 = ct * 128;

    f32x4 acc[4][4];
    #pragma unroll
    for (int im = 0; im < 4; ++im)
        #pragma unroll
        for (int jn = 0; jn < 4; ++jn)
            acc[im][jn] = (f32x4){0.f, 0.f, 0.f, 0.f};

    for (int kk = 0; kk < DIM; kk += 32) {
        // stage 128x32B fp8 tiles, 16 B/lane direct global->LDS, 1 chunk/lane/tile.
        // 16-B half-row position rotated by (row>>2)&1 -> residual 2-way LDS
        // conflict on the b64 fragment reads (free per m136).
        {
            int r = t >> 1, h = t & 1;
            int koff = ((h + ((r >> 2) & 1)) & 1) * 16;
            const unsigned char* ga = A  + (size_t)(row0 + r) * DIM + kk + koff;
            const unsigned char* gb = Bm + (size_t)(col0 + r) * DIM + kk + koff;
            __builtin_amdgcn_global_load_lds(
                (const __attribute__((address_space(1))) void*)ga,
                (__attribute__((address_space(3))) void*)(sA + t * 16), 16, 0, 0);
            __builtin_amdgcn_global_load_lds(
                (const __attribute__((address_space(1))) void*)gb,
                (__attribute__((address_space(3))) void*)(sB + t * 16), 16, 0, 0);
        }
        __syncthreads();

        long long af[4], bfr[4];
        const int hk = quad >> 1, q8 = (quad & 1) * 8;
        #pragma unroll
        for (int im = 0; im < 4; ++im) {
            int row = wm * 64 + im * 16 + l16;
            int hl  = (hk + ((row >> 2) & 1)) & 1;
            af[im] = *(const long long*)&sA[row * 32 + hl * 16 + q8];
        }
        #pragma unroll
        for (int jn = 0; jn < 4; ++jn) {
            int row = wn * 64 + jn * 16 + l16;
            int hl  = (hk + ((row >> 2) & 1)) & 1;
            bfr[jn] = *(const long long*)&sB[row * 32 + hl * 16 + q8];
        }

        #pragma unroll
        for (int im = 0; im < 4; ++im)
            #pragma unroll
            for (int jn = 0; jn < 4; ++jn)
                acc[im][jn] = __builtin_amdgcn_mfma_f32_16x16x32_fp8_fp8(
                    af[im], bfr[jn], acc[im][jn], 0, 0, 0);
        __syncthreads();
    }

    // epilogue: logits, exp, row sums (+ col sums), diag capture/mask
    float csum[4] = {0.f, 0.f, 0.f, 0.f};
    #pragma unroll
    for (int im = 0; im < 4; ++im) {
        #pragma unroll
        for (int r = 0; r < 4; ++r) {
            const int gi = row0 + wm * 64 + im * 16 + quad * 4 + r;
            float rsum = 0.f;
            #pragma unroll
            for (int jn = 0; jn < 4; ++jn) {
                const int gj = col0 + wn * 64 + jn * 16 + l16;
                float logit = acc[im][jn][r] * LOGIT_SCALE;
                bool isDiag = (gi == gj);
                if (captureDiag && isDiag) diag[gi] = logit;
                float e = __expf(logit);
                if (maskDiag && isDiag) e = 0.f;
                rsum += e;
                csum[jn] += e;
            }
            rsum += __shfl_xor(rsum, 1);
            rsum += __shfl_xor(rsum, 2);
            rsum += __shfl_xor(rsum, 4);
            rsum += __shfl_xor(rsum, 8);
            if (l16 == 0) atomicAdd(&S[rowTarget * BATCH + gi], rsum);
        }
    }
    if (doColsum) {
        #pragma unroll
        for (int jn = 0; jn < 4; ++jn) {
            float c = csum[jn];
            c += __shfl_xor(c, 16);
            c += __shfl_xor(c, 32);
            if (quad == 0) {
                const int gj = col0 + wn * 64 + jn * 16 + l16;
                atomicAdd(&S[colTarget * BATCH + gj], c);
            }
        }
    }
}

// ---------------- Kernel 3: finalize loss (single block) --------------------
// v4: 1024 threads (was 256) -> serial logf chain 16 -> 4 iterations.
__global__ __launch_bounds__(1024) void finalize(
    const float* __restrict__ S, const float* __restrict__ diag,
    float* __restrict__ out)
{
    int t = threadIdx.x;
    float local = 0.f;
    for (int i = t; i < BATCH; i += 1024) {
        float lse_a = logf(S[i]);
        float lse_b = logf(S[BATCH + i]);
        local += 0.5f * (lse_a + lse_b) - diag[i];
    }
    #pragma unroll
    for (int off = 32; off >= 1; off >>= 1) local += __shfl_xor(local, off);
    __shared__ float wsum[16];
    if ((t & 63) == 0) wsum[t >> 6] = local;
    __syncthreads();
    if (t == 0) {
        float tot = 0.f;
        #pragma unroll
        for (int w = 0; w < 16; ++w) tot += wsum[w];
        out[0] = tot / (float)BATCH;
    }
}

extern "C" void kernel_launch(void* const* d_in, const int* in_sizes, int n_in,
                              void* d_out, int out_size, void* d_ws, size_t ws_size,
                              hipStream_t stream)
{
    const float* emb  = (const float*)d_in[0];
    const int* links  = (const int*)d_in[1];

    char* ws = (char*)d_ws;
    unsigned char* hn1 = (unsigned char*)ws;                         // 3.1 MB fp8
    unsigned char* hn2 = (unsigned char*)(ws + (size_t)BATCH * DIM); // 3.1 MB fp8
    float* S    = (float*)(ws + (size_t)BATCH * DIM * 2);            // 2*4096 f32
    float* diag = (float*)(ws + (size_t)BATCH * DIM * 2 + 2 * BATCH * 4); // 4096 f32

    hipMemsetAsync(S, 0, 2 * BATCH * sizeof(float), stream);

    gather_norm<<<dim3(2 * BATCH / 4), 256, 0, stream>>>(emb, links, hn1, hn2);
    gram_sym<<<dim3(32, 32, 3), 256, 0, stream>>>(hn1, hn2, S, diag);
    finalize<<<1, 1024, 0, stream>>>(S, diag, (float*)d_out);
}

// Round 5
// 402.541 us; speedup vs baseline: 1.1532x; 1.0585x over previous
//
#include <hip/hip_runtime.h>
#include <hip/hip_bf16.h>
#include <math.h>

#define NUM_ENT 100000
#define DIM 768
#define BATCH 4096
#define INV_TAU 20.0f
#define QSCALE 256.0f                                  // i8 quant scale (pow2, exact)
#define LOGIT_SCALE (INV_TAU / (QSCALE * QSCALE))      // undo QSCALE^2 after MFMA

typedef __attribute__((ext_vector_type(4))) int i32x4;     // i8-MFMA accum / operands

__device__ inline unsigned int pack_i8x4(float a, float b, float c, float d) {
    int ia = __float2int_rn(fminf(fmaxf(a, -127.f), 127.f));
    int ib = __float2int_rn(fminf(fmaxf(b, -127.f), 127.f));
    int ic = __float2int_rn(fminf(fmaxf(c, -127.f), 127.f));
    int id = __float2int_rn(fminf(fmaxf(d, -127.f), 127.f));
    return (unsigned int)((ia & 0xff) | ((ib & 0xff) << 8) |
                          ((ic & 0xff) << 16) | ((id & 0xff) << 24));
}

// ------- Kernel 1: gather + L2-normalize -> int8 (scaled by 256) ------------
// One wave per row; lane loads 3x float4, shfl_xor reduce, no LDS/barrier.
// Also zeroes S (blocks 0..31) so the separate memset dispatch is dropped.
__global__ __launch_bounds__(256) void gather_norm(
    const float* __restrict__ emb, const int* __restrict__ links,
    unsigned char* __restrict__ hn1, unsigned char* __restrict__ hn2,
    float* __restrict__ S)
{
    const int t    = threadIdx.x;
    const int wave = t >> 6;
    const int lane = t & 63;
    if (blockIdx.x < 32) S[blockIdx.x * 256 + t] = 0.f;   // 8192 f32 = 2*BATCH

    const int rowId = blockIdx.x * 4 + wave;   // 0 .. 2*BATCH-1
    const int b     = rowId >> 1;
    const int which = rowId & 1;
    const int src   = links[2 * b + which];
    const float* srcRow = emb + (size_t)src * DIM;

    float4 v0 = ((const float4*)srcRow)[lane];
    float4 v1 = ((const float4*)srcRow)[lane + 64];
    float4 v2 = ((const float4*)srcRow)[lane + 128];

    float ss = v0.x * v0.x + v0.y * v0.y + v0.z * v0.z + v0.w * v0.w
             + v1.x * v1.x + v1.y * v1.y + v1.z * v1.z + v1.w * v1.w
             + v2.x * v2.x + v2.y * v2.y + v2.z * v2.z + v2.w * v2.w;
    #pragma unroll
    for (int off = 32; off >= 1; off >>= 1) ss += __shfl_xor(ss, off);
    const float scale = rsqrtf(ss) * QSCALE;

    unsigned char* dst = (which ? hn2 : hn1) + (size_t)b * DIM;
    ((unsigned int*)dst)[lane] =
        pack_i8x4(v0.x * scale, v0.y * scale, v0.z * scale, v0.w * scale);
    ((unsigned int*)dst)[lane + 64] =
        pack_i8x4(v1.x * scale, v1.y * scale, v1.z * scale, v1.w * scale);
    ((unsigned int*)dst)[lane + 128] =
        pack_i8x4(v2.x * scale, v2.y * scale, v2.z * scale, v2.w * scale);
}

// ------- Kernel 2: symmetric gram (i8 MFMA, K=64) + exp row/col-sum ---------
// grid: (32 colTile, 32 rowTile, 3 matrices). block: 256 (4 waves).
// matId 0: ab = h1 x h2^T  full     : rowsum->S_a, colsum->S_b, diag capture
// matId 1: aa = h1 x h1^T  upper-tri: rowsum->S_a[gi]; off-diag also colsum->S_a[gj]
// matId 2: bb = h2 x h2^T  upper-tri: rowsum->S_b[gi]; off-diag also colsum->S_b[gj]
//
// v6 = v5's i8/BK=64 with the G21 violation FIXED: global_load_lds writes
// LDS at wave-uniform base + lane*16 only, so the LDS destination must be
// LINEAR in thread id (idx*16); the bank-derotation is applied on the
// per-lane GLOBAL source address instead (round-1-verified pattern).
// Content at row r, position p is logical chunk c=(p-(r>>1))&3; read side
// fetches logical chunk quad at p=(quad+(r>>1))&3 -> rows 0..7 cover all 32
// banks once => 2-way conflict on ds_read_b128 (free, m136).
__global__ __launch_bounds__(256) void gram_sym(
    const unsigned char* __restrict__ hn1, const unsigned char* __restrict__ hn2,
    float* __restrict__ S, float* __restrict__ diag)
{
    const int ct = blockIdx.x;
    const int rt = blockIdx.y;
    const int matId = blockIdx.z;
    if (matId > 0 && ct < rt) return;   // symmetric matrices: upper triangle only

    const unsigned char* A  = (matId == 2) ? hn2 : hn1;
    const unsigned char* Bm = (matId == 1) ? hn1 : hn2;
    const int  rowTarget = (matId == 2) ? 1 : 0;
    const int  colTarget = (matId == 1) ? 0 : 1;
    const bool maskDiag  = (matId > 0) && (rt == ct);
    const bool doColsum  = (matId == 0) || (rt != ct);
    const bool captureDiag = (matId == 0);

    __shared__ unsigned char sA[128 * 64];   // 8 KB (i8: 128 rows x 64 K-bytes)
    __shared__ unsigned char sB[128 * 64];   // 8 KB

    const int t    = threadIdx.x;
    const int lane = t & 63;
    const int wave = t >> 6;
    const int wm   = wave >> 1, wn = wave & 1;
    const int quad = lane >> 4, l16 = lane & 15;
    const int row0 = rt * 128;
    const int col0 = ct * 128;

    i32x4 acc[4][4];
    #pragma unroll
    for (int im = 0; im < 4; ++im)
        #pragma unroll
        for (int jn = 0; jn < 4; ++jn)
            acc[im][jn] = (i32x4){0, 0, 0, 0};

    for (int kk = 0; kk < DIM; kk += 64) {
        // stage 128x64B per matrix: 2 rounds x 256 threads x 16B.
        // idx = rd*256+t -> LDS dest idx*16 (LINEAR, required by G21);
        // row r = idx>>2, position p = idx&3, logical chunk c = (p-(r>>1))&3
        // fetched from global.
        #pragma unroll
        for (int rd = 0; rd < 2; ++rd) {
            const int idx = rd * 256 + t;
            const int r   = idx >> 2;
            const int p   = idx & 3;
            const int c   = (p - (r >> 1)) & 3;
            const unsigned char* ga = A  + (size_t)(row0 + r) * DIM + kk + c * 16;
            const unsigned char* gb = Bm + (size_t)(col0 + r) * DIM + kk + c * 16;
            __builtin_amdgcn_global_load_lds(
                (const __attribute__((address_space(1))) void*)ga,
                (__attribute__((address_space(3))) void*)(sA + idx * 16), 16, 0, 0);
            __builtin_amdgcn_global_load_lds(
                (const __attribute__((address_space(1))) void*)gb,
                (__attribute__((address_space(3))) void*)(sB + idx * 16), 16, 0, 0);
        }
        __syncthreads();

        i32x4 af[4], bfr[4];
        #pragma unroll
        for (int im = 0; im < 4; ++im) {
            int row = wm * 64 + im * 16 + l16;
            int p   = (quad + (row >> 1)) & 3;
            const int4 x = *(const int4*)&sA[row * 64 + p * 16];
            af[im] = (i32x4){x.x, x.y, x.z, x.w};
        }
        #pragma unroll
        for (int jn = 0; jn < 4; ++jn) {
            int row = wn * 64 + jn * 16 + l16;
            int p   = (quad + (row >> 1)) & 3;
            const int4 x = *(const int4*)&sB[row * 64 + p * 16];
            bfr[jn] = (i32x4){x.x, x.y, x.z, x.w};
        }

        #pragma unroll
        for (int im = 0; im < 4; ++im)
            #pragma unroll
            for (int jn = 0; jn < 4; ++jn)
                acc[im][jn] = __builtin_amdgcn_mfma_i32_16x16x64_i8(
                    af[im], bfr[jn], acc[im][jn], 0, 0, 0);
        __syncthreads();
    }

    // epilogue: logits, exp, row sums (+ col sums), diag capture/mask
    float csum[4] = {0.f, 0.f, 0.f, 0.f};
    #pragma unroll
    for (int im = 0; im < 4; ++im) {
        #pragma unroll
        for (int rr = 0; rr < 4; ++rr) {
            const int gi = row0 + wm * 64 + im * 16 + quad * 4 + rr;
            float rsum = 0.f;
            #pragma unroll
            for (int jn = 0; jn < 4; ++jn) {
                const int gj = col0 + wn * 64 + jn * 16 + l16;
                float logit = (float)acc[im][jn][rr] * LOGIT_SCALE;
                bool isDiag = (gi == gj);
                if (captureDiag && isDiag) diag[gi] = logit;
                float e = __expf(logit);
                if (maskDiag && isDiag) e = 0.f;
                rsum += e;
                csum[jn] += e;
            }
            rsum += __shfl_xor(rsum, 1);
            rsum += __shfl_xor(rsum, 2);
            rsum += __shfl_xor(rsum, 4);
            rsum += __shfl_xor(rsum, 8);
            if (l16 == 0) atomicAdd(&S[rowTarget * BATCH + gi], rsum);
        }
    }
    if (doColsum) {
        #pragma unroll
        for (int jn = 0; jn < 4; ++jn) {
            float c = csum[jn];
            c += __shfl_xor(c, 16);
            c += __shfl_xor(c, 32);
            if (quad == 0) {
                const int gj = col0 + wn * 64 + jn * 16 + l16;
                atomicAdd(&S[colTarget * BATCH + gj], c);
            }
        }
    }
}

// ---------------- Kernel 3: finalize loss (single block) --------------------
__global__ __launch_bounds__(1024) void finalize(
    const float* __restrict__ S, const float* __restrict__ diag,
    float* __restrict__ out)
{
    int t = threadIdx.x;
    float local = 0.f;
    for (int i = t; i < BATCH; i += 1024) {
        float lse_a = logf(S[i]);
        float lse_b = logf(S[BATCH + i]);
        local += 0.5f * (lse_a + lse_b) - diag[i];
    }
    #pragma unroll
    for (int off = 32; off >= 1; off >>= 1) local += __shfl_xor(local, off);
    __shared__ float wsum[16];
    if ((t & 63) == 0) wsum[t >> 6] = local;
    __syncthreads();
    if (t == 0) {
        float tot = 0.f;
        #pragma unroll
        for (int w = 0; w < 16; ++w) tot += wsum[w];
        out[0] = tot / (float)BATCH;
    }
}

extern "C" void kernel_launch(void* const* d_in, const int* in_sizes, int n_in,
                              void* d_out, int out_size, void* d_ws, size_t ws_size,
                              hipStream_t stream)
{
    const float* emb  = (const float*)d_in[0];
    const int* links  = (const int*)d_in[1];

    char* ws = (char*)d_ws;
    unsigned char* hn1 = (unsigned char*)ws;                         // 3.1 MB i8
    unsigned char* hn2 = (unsigned char*)(ws + (size_t)BATCH * DIM); // 3.1 MB i8
    float* S    = (float*)(ws + (size_t)BATCH * DIM * 2);            // 2*4096 f32
    float* diag = (float*)(ws + (size_t)BATCH * DIM * 2 + 2 * BATCH * 4); // 4096 f32

    gather_norm<<<dim3(2 * BATCH / 4), 256, 0, stream>>>(emb, links, hn1, hn2, S);
    gram_sym<<<dim3(32, 32, 3), 256, 0, stream>>>(hn1, hn2, S, diag);
    finalize<<<1, 1024, 0, stream>>>(S, diag, (float*)d_out);
}